// Round 2
// baseline (250.395 us; speedup 1.0000x reference)
//
#include <hip/hip_runtime.h>

#define T_SEQ 4096
#define NDIM 64
#define BH 32

typedef short short8 __attribute__((ext_vector_type(8)));
typedef float f32x16 __attribute__((ext_vector_type(16)));

static __device__ __forceinline__ unsigned short f2bf(float x) {
    union { float f; unsigned u; } v; v.f = x;
    return (unsigned short)((v.u + 0x8000u) >> 16);
}

static __device__ __forceinline__ f32x16 mfma32(short8 a, short8 b, f32x16 c) {
    return __builtin_amdgcn_mfma_f32_32x32x16_bf16(a, b, c, 0, 0, 0);
}

// ---------------- Kernel 1: RoPE(Q) -> bf16 qr[bh][t][64] ----------------
__global__ __launch_bounds__(256) void rope_kernel(const float* __restrict__ Q,
                                                   unsigned short* __restrict__ qr) {
    int p = blockIdx.x * 256 + threadIdx.x;          // pair index, B*H*T*32 total
    const int total = BH * T_SEQ * 32;
    if (p >= total) return;
    int np = p & 31;                                  // pair within head-dim
    int t  = (p >> 5) & (T_SEQ - 1);
    float2 q = ((const float2*)Q)[p];
    // freq = theta^(-tq/N)/(2pi), theta=2^16, tq=2*np, N=64 -> 2^(-np/2)/(2pi)
    float freq = exp2f(-0.5f * (float)np) * 0.15915494309189535f;
    float ph = (float)t * freq;
    float ang = (ph - floorf(ph)) * 6.283185307179586f;
    float s, c;
    __sincosf(ang, &s, &c);
    float r0 = q.x * c - q.y * s;
    float r1 = q.y * c + q.x * s;
    unsigned pk = (unsigned)f2bf(r0) | ((unsigned)f2bf(r1) << 16);
    ((unsigned*)qr)[p] = pk;
}

// ------- Kernel 2: V -> bf16 vt[bh][d][t], pre-scaled by N^-0.5 = 0.125 -------
__global__ __launch_bounds__(256) void vtrans_kernel(const float* __restrict__ V,
                                                     unsigned short* __restrict__ vt) {
    __shared__ float tile[64][65];
    int bh = blockIdx.y;
    int s0 = blockIdx.x * 64;
    const float* vsrc = V + ((size_t)bh * T_SEQ + s0) * NDIM;
    int tid = threadIdx.x;
#pragma unroll
    for (int i = 0; i < 4; ++i) {
        int e = (i * 256 + tid) * 4;
        int row = e >> 6, col = e & 63;
        float4 d4 = *(const float4*)(vsrc + e);
        tile[row][col + 0] = d4.x; tile[row][col + 1] = d4.y;
        tile[row][col + 2] = d4.z; tile[row][col + 3] = d4.w;
    }
    __syncthreads();
    unsigned short* vdst = vt + (size_t)bh * NDIM * T_SEQ + s0;
#pragma unroll
    for (int i = 0; i < 4; ++i) {
        int e = (i * 256 + tid) * 4;
        int d = e >> 6, sc = e & 63;
        ushort4 o;
        o.x = f2bf(tile[sc + 0][d] * 0.125f);
        o.y = f2bf(tile[sc + 1][d] * 0.125f);
        o.z = f2bf(tile[sc + 2][d] * 0.125f);
        o.w = f2bf(tile[sc + 3][d] * 0.125f);
        *(ushort4*)(vdst + (size_t)d * T_SEQ + sc) = o;
    }
}

// ---------------- Kernel 3: main masked attention (no softmax) ----------------
// Per block: one (bh, 128-row q-tile). 4 waves.
// GEMM1 computes S^T[s][t] = K·Q^T with A/B frags read DIRECTLY from global qr
// (no LDS staging, no staging barrier). C-layout of S^T gives contiguous-s regs,
// so P is written to LDS ps[t][s] with packed b64 writes. GEMM2: O += P·V with
// P A-frags from LDS (b128) and V B-frags from global vt (L2).
#define LDP 136   // bf16 elems per t-row: 128 + 8 pad (row stride 272 B, 16B-aligned)

__global__ __launch_bounds__(256, 3) void attn_kernel(const unsigned short* __restrict__ qr,
                                                      const unsigned short* __restrict__ vt,
                                                      float* __restrict__ out) {
    __shared__ unsigned short ps[128 * LDP];   // P tile bf16, [t][s]

    const int tid = threadIdx.x;
    const int lane = tid & 63;
    const int w = tid >> 6;
    const int ws = w >> 1, wt = w & 1;        // S-phase: s-tile pair, t-tile pair
    const int l31 = lane & 31, hi = lane >> 5;

    const int blk = blockIdx.x;
    const int bh = blk & 31;
    const int qb = 31 - (blk >> 5);           // longest blocks first
    const int t0 = qb * 128;

    const unsigned short* qr_h = qr + (size_t)bh * (T_SEQ * NDIM);
    const unsigned short* vt_h = vt + (size_t)bh * (NDIM * T_SEQ);
    float* out_h = out + (size_t)bh * (T_SEQ * NDIM);

    // Persistent Q B-fragments: B[k=d][n=t] = Q[t][d]; lane n=t, k contiguous.
    short8 bq[2][4];
#pragma unroll
    for (int tt2 = 0; tt2 < 2; ++tt2)
#pragma unroll
        for (int kc = 0; kc < 4; ++kc)
            bq[tt2][kc] = *(const short8*)(qr_h +
                (size_t)(t0 + (2 * wt + tt2) * 32 + l31) * NDIM + kc * 16 + hi * 8);

    f32x16 oacc[2];
#pragma unroll
    for (int m = 0; m < 2; ++m)
#pragma unroll
        for (int r = 0; r < 16; ++r) oacc[m][r] = 0.0f;

    for (int sb = 0; sb <= qb; ++sb) {
        const int s0 = sb * 128;

        // K A-fragments from global: A[m=s][k=d] = K[s][d]; lane m=s, k contiguous.
        short8 ak[2][4];
#pragma unroll
        for (int st2 = 0; st2 < 2; ++st2)
#pragma unroll
            for (int kc = 0; kc < 4; ++kc)
                ak[st2][kc] = *(const short8*)(qr_h +
                    (size_t)(s0 + (2 * ws + st2) * 32 + l31) * NDIM + kc * 16 + hi * 8);

        // ---- S-phase: sacc[st2][tt2] = S^T tile (m=s, n=t) ----
        f32x16 sacc[2][2];
#pragma unroll
        for (int a = 0; a < 2; ++a)
#pragma unroll
            for (int b = 0; b < 2; ++b)
#pragma unroll
                for (int r = 0; r < 16; ++r) sacc[a][b][r] = 0.0f;
#pragma unroll
        for (int st2 = 0; st2 < 2; ++st2)
#pragma unroll
            for (int tt2 = 0; tt2 < 2; ++tt2)
#pragma unroll
                for (int kc = 0; kc < 4; ++kc)
                    sacc[st2][tt2] = mfma32(ak[st2][kc], bq[tt2][kc], sacc[st2][tt2]);

        // V B-fragments from global (issued early; latency hides under barrier+P-write)
        short8 vf[8];
#pragma unroll
        for (int kc = 0; kc < 8; ++kc)
            vf[kc] = *(const short8*)(vt_h + (size_t)((w & 1) * 32 + l31) * T_SEQ +
                                      s0 + kc * 16 + hi * 8);

        __syncthreads();   // prev iteration's ps reads complete before overwrite

        // ---- write P to LDS ps[t][s], packed b64 (4 bf16 per write) ----
        // C-layout of S^T: col = t = l31, row = s = (r&3) + 8*(r>>2) + 4*hi.
        const bool diag = (sb == qb);
        if (!diag) {
#pragma unroll
            for (int st2 = 0; st2 < 2; ++st2) {
                const int st = 2 * ws + st2;
#pragma unroll
                for (int tt2 = 0; tt2 < 2; ++tt2) {
                    const int trow = (2 * wt + tt2) * 32 + l31;
                    unsigned short* pbase = &ps[trow * LDP + st * 32 + 4 * hi];
#pragma unroll
                    for (int g = 0; g < 4; ++g) {
                        ushort4 pk;
                        pk.x = f2bf(sacc[st2][tt2][4 * g + 0]);
                        pk.y = f2bf(sacc[st2][tt2][4 * g + 1]);
                        pk.z = f2bf(sacc[st2][tt2][4 * g + 2]);
                        pk.w = f2bf(sacc[st2][tt2][4 * g + 3]);
                        *(ushort4*)(pbase + 8 * g) = pk;
                    }
                }
            }
        } else {
#pragma unroll
            for (int st2 = 0; st2 < 2; ++st2) {
                const int st = 2 * ws + st2;
#pragma unroll
                for (int tt2 = 0; tt2 < 2; ++tt2) {
                    const int trow = (2 * wt + tt2) * 32 + l31;
                    unsigned short* pbase = &ps[trow * LDP + st * 32 + 4 * hi];
#pragma unroll
                    for (int g = 0; g < 4; ++g) {
                        ushort4 pk;
#pragma unroll
                        for (int e = 0; e < 4; ++e) {
                            const int srow = st * 32 + 8 * g + 4 * hi + e;
                            float v = sacc[st2][tt2][4 * g + e];
                            if (srow >= trow) v = 0.0f;   // keep s < t only
                            ((unsigned short*)&pk)[e] = f2bf(v);
                        }
                        *(ushort4*)(pbase + 8 * g) = pk;
                    }
                }
            }
        }
        __syncthreads();

        // ---- O-phase: oacc += P * V ----
        const int wm = w >> 1, wn = w & 1;
#pragma unroll
        for (int kc = 0; kc < 8; ++kc) {
            short8 pf0 = *(const short8*)&ps[((2 * wm + 0) * 32 + l31) * LDP +
                                             kc * 16 + hi * 8];
            short8 pf1 = *(const short8*)&ps[((2 * wm + 1) * 32 + l31) * LDP +
                                             kc * 16 + hi * 8];
            oacc[0] = mfma32(pf0, vf[kc], oacc[0]);
            oacc[1] = mfma32(pf1, vf[kc], oacc[1]);
        }
        (void)wn;
    }

    // ---- epilogue: fp32 store, C-layout ----
    const int wm = w >> 1, wn = w & 1;
#pragma unroll
    for (int mt2 = 0; mt2 < 2; ++mt2) {
        const int mt = 2 * wm + mt2;
#pragma unroll
        for (int r = 0; r < 16; ++r) {
            const int rl = (r & 3) + 8 * (r >> 2) + 4 * hi;
            out_h[(size_t)(t0 + mt * 32 + rl) * NDIM + wn * 32 + l31] = oacc[mt2][r];
        }
    }
}

extern "C" void kernel_launch(void* const* d_in, const int* in_sizes, int n_in,
                              void* d_out, int out_size, void* d_ws, size_t ws_size,
                              hipStream_t stream) {
    (void)in_sizes; (void)n_in; (void)out_size; (void)ws_size;
    const float* Q = (const float*)d_in[0];
    const float* V = (const float*)d_in[1];
    float* out = (float*)d_out;

    unsigned short* qr = (unsigned short*)d_ws;            // 16 MB bf16
    unsigned short* vt = qr + (size_t)BH * T_SEQ * NDIM;   // 16 MB bf16

    const int total_pairs = BH * T_SEQ * 32;
    rope_kernel<<<(total_pairs + 255) / 256, 256, 0, stream>>>(Q, qr);
    vtrans_kernel<<<dim3(T_SEQ / 64, BH), 256, 0, stream>>>(V, vt);
    attn_kernel<<<BH * 32, 256, 0, stream>>>(qr, vt, out);
}

// Round 4
// 181.046 us; speedup vs baseline: 1.3830x; 1.3830x over previous
//
#include <hip/hip_runtime.h>

#define T_SEQ 4096
#define NDIM 64
#define BH 32
#define TN (T_SEQ * NDIM)

typedef short short8 __attribute__((ext_vector_type(8)));
typedef float f32x16 __attribute__((ext_vector_type(16)));

static __device__ __forceinline__ unsigned short f2bf(float x) {
    union { float f; unsigned u; } v; v.f = x;
    return (unsigned short)((v.u + 0x8000u) >> 16);
}

static __device__ __forceinline__ f32x16 mfma32(short8 a, short8 b, f32x16 c) {
    return __builtin_amdgcn_mfma_f32_32x32x16_bf16(a, b, c, 0, 0, 0);
}

// Fragment layout for Q (serves both A- and B-frags of GEMM1):
//   qf elem((row r, kc, l31, hi, j)) = ((r>>5)*4 + kc)*512 + ((r&31)*2 + hi)*8 + j
// A wave's frag load (l31 stride 16 elems, hi stride 8) is one contiguous 1KB read.

// ---------- Kernel 1: RoPE(Q) -> bf16 qf in fragment layout ----------
__global__ __launch_bounds__(256) void rope_kernel(const float* __restrict__ Q,
                                                   unsigned short* __restrict__ qf) {
    const int bhtb = blockIdx.x;            // bh*128 + tb
    const int tb = bhtb & 127;              // 32-row block within T
    const int bh = bhtb >> 7;
    const int np = threadIdx.x & 31;        // feature pair 0..31
    const int tg = threadIdx.x >> 5;        // 0..7
    const float freq = exp2f(-0.5f * (float)np) * 0.15915494309189535f;
    const int kc = np >> 3, hi = (np >> 2) & 1, jw = np & 3;
    const float2* qsrc = (const float2*)(Q + ((size_t)bh * T_SEQ + tb * 32) * NDIM);
    unsigned* qdst = (unsigned*)(qf + (size_t)bh * TN + (size_t)tb * 32 * NDIM);
#pragma unroll
    for (int it = 0; it < 4; ++it) {
        const int tl = tg * 4 + it;         // 0..31
        const int t = tb * 32 + tl;
        float2 q = qsrc[tl * 32 + np];
        float ph = (float)t * freq;
        float ang = (ph - floorf(ph)) * 6.283185307179586f;
        float s, c;
        __sincosf(ang, &s, &c);
        float r0 = q.x * c - q.y * s;
        float r1 = q.y * c + q.x * s;
        unsigned pk = (unsigned)f2bf(r0) | ((unsigned)f2bf(r1) << 16);
        qdst[kc * 256 + (tl * 2 + hi) * 4 + jw] = pk;
    }
}

// ---------- Kernel 2: V -> bf16 vfrag (GEMM2 B-frag layout), scaled 0.125 ----------
//   vfrag elem = bh*TN + sb*8192 + (kc*128 + d*2 + hi)*8 + j ,  value V[s0+kc*16+hi*8+j][d]*0.125
__global__ __launch_bounds__(256) void vtrans_kernel(const float* __restrict__ V,
                                                     unsigned short* __restrict__ vfr) {
    __shared__ float tile[128 * 65];
    const int sb = blockIdx.x;              // 0..31 (128-s block)
    const int bh = blockIdx.y;
    const int tid = threadIdx.x;
    const float* vsrc = V + ((size_t)bh * T_SEQ + sb * 128) * NDIM;
#pragma unroll
    for (int i = 0; i < 8; ++i) {
        int e = (i * 256 + tid) * 4;
        int row = e >> 6, col = e & 63;
        float4 d4 = *(const float4*)(vsrc + e);
        tile[row * 65 + col + 0] = d4.x; tile[row * 65 + col + 1] = d4.y;
        tile[row * 65 + col + 2] = d4.z; tile[row * 65 + col + 3] = d4.w;
    }
    __syncthreads();
    unsigned short* dst = vfr + (size_t)bh * TN + (size_t)sb * 8192;
#pragma unroll
    for (int u = 0; u < 4; ++u) {
        int g = u * 256 + tid;              // 0..1023: kc*128 + d*2 + hi
        int kc = g >> 7, dh = g & 127;
        int d = dh >> 1, hh = dh & 1;
        int sbase = kc * 16 + hh * 8;
        ushort4 o0, o1;
        o0.x = f2bf(tile[(sbase + 0) * 65 + d] * 0.125f);
        o0.y = f2bf(tile[(sbase + 1) * 65 + d] * 0.125f);
        o0.z = f2bf(tile[(sbase + 2) * 65 + d] * 0.125f);
        o0.w = f2bf(tile[(sbase + 3) * 65 + d] * 0.125f);
        o1.x = f2bf(tile[(sbase + 4) * 65 + d] * 0.125f);
        o1.y = f2bf(tile[(sbase + 5) * 65 + d] * 0.125f);
        o1.z = f2bf(tile[(sbase + 6) * 65 + d] * 0.125f);
        o1.w = f2bf(tile[(sbase + 7) * 65 + d] * 0.125f);
        *(ushort4*)(dst + g * 8 + 0) = o0;
        *(ushort4*)(dst + g * 8 + 4) = o1;
    }
}

// ---------- Kernel 3: masked attention, all frag loads coalesced ----------
#define LDP 136

__global__ __launch_bounds__(256, 2) void attn_kernel(const unsigned short* __restrict__ qf,
                                                      const unsigned short* __restrict__ vfr,
                                                      float* __restrict__ out) {
    __shared__ unsigned short ps[128 * LDP];   // P tile [t][s], col shift +(t&8)

    const int tid = threadIdx.x;
    const int lane = tid & 63;
    const int w = tid >> 6;
    const int ws = w >> 1, wt = w & 1;         // also O-phase wm/wn
    const int l31 = lane & 31, hi = lane >> 5;
    const int swz = (l31 & 8);                 // ps column shift for this lane's rows

    const int blk = blockIdx.x;
    const int bh = blk & 31;
    const int qb = 31 - (blk >> 5);            // longest q-tiles first
    const int t0 = qb * 128;

    const unsigned short* qfh = qf + (size_t)bh * TN;
    const unsigned short* vfh = vfr + (size_t)bh * TN;
    float* out_h = out + (size_t)bh * TN;

    const int lhx16 = (l31 * 2 + hi) * 8;      // lane offset inside a frag chunk

    // Persistent Q B-frags for this wave's t-subtiles
    short8 bq[2][4];
#pragma unroll
    for (int tt2 = 0; tt2 < 2; ++tt2) {
        const int r32 = (t0 >> 5) + 2 * wt + tt2;
#pragma unroll
        for (int kc = 0; kc < 4; ++kc)
            bq[tt2][kc] = *(const short8*)(qfh + (size_t)(r32 * 4 + kc) * 512 + lhx16);
    }

    f32x16 oacc[2];
#pragma unroll
    for (int m = 0; m < 2; ++m)
#pragma unroll
        for (int r = 0; r < 16; ++r) oacc[m][r] = 0.0f;

    // K A-frags for sb=0
    short8 ak[2][4];
#pragma unroll
    for (int st2 = 0; st2 < 2; ++st2) {
        const int r32 = 2 * ws + st2;
#pragma unroll
        for (int kc = 0; kc < 4; ++kc)
            ak[st2][kc] = *(const short8*)(qfh + (size_t)(r32 * 4 + kc) * 512 + lhx16);
    }

    for (int sb = 0; sb <= qb; ++sb) {
        // V B-frags (coalesced 1KB wave-loads) — issue early, drain under barriers
        // d-subtile = wt: index = sb*8192 + kc*1024 + wt*512 + (l31*2+hi)*8
        short8 vf[8];
#pragma unroll
        for (int kc = 0; kc < 8; ++kc)
            vf[kc] = *(const short8*)(vfh + (size_t)sb * 8192 + (size_t)kc * 1024 +
                                      (size_t)wt * 512 + lhx16);

        // ---- S-phase: sacc[st2][tt2] = S^T tile (m=s, n=t) ----
        f32x16 sacc[2][2];
#pragma unroll
        for (int a = 0; a < 2; ++a)
#pragma unroll
            for (int b = 0; b < 2; ++b)
#pragma unroll
                for (int r = 0; r < 16; ++r) sacc[a][b][r] = 0.0f;
#pragma unroll
        for (int st2 = 0; st2 < 2; ++st2)
#pragma unroll
            for (int tt2 = 0; tt2 < 2; ++tt2)
#pragma unroll
                for (int kc = 0; kc < 4; ++kc)
                    sacc[st2][tt2] = mfma32(ak[st2][kc], bq[tt2][kc], sacc[st2][tt2]);

        // Prefetch next K A-frags; drains during P-write + barriers + O-phase
        short8 akn[2][4];
        if (sb < qb) {
#pragma unroll
            for (int st2 = 0; st2 < 2; ++st2) {
                const int r32 = ((sb + 1) * 4) + 2 * ws + st2;
#pragma unroll
                for (int kc = 0; kc < 4; ++kc)
                    akn[st2][kc] = *(const short8*)(qfh + (size_t)(r32 * 4 + kc) * 512 + lhx16);
            }
        }

        __syncthreads();   // prev iteration's ps reads complete before overwrite

        // ---- write P to ps[t][s + (t&8)], packed b64 writes ----
        const bool diag = (sb == qb);
#pragma unroll
        for (int st2 = 0; st2 < 2; ++st2) {
            const int st = 2 * ws + st2;
#pragma unroll
            for (int tt2 = 0; tt2 < 2; ++tt2) {
                const int trow = (2 * wt + tt2) * 32 + l31;
                unsigned short* pbase = &ps[trow * LDP + st * 32 + 4 * hi + swz];
                if (!diag) {
#pragma unroll
                    for (int g = 0; g < 4; ++g) {
                        ushort4 pk;
                        pk.x = f2bf(sacc[st2][tt2][4 * g + 0]);
                        pk.y = f2bf(sacc[st2][tt2][4 * g + 1]);
                        pk.z = f2bf(sacc[st2][tt2][4 * g + 2]);
                        pk.w = f2bf(sacc[st2][tt2][4 * g + 3]);
                        *(ushort4*)(pbase + 8 * g) = pk;
                    }
                } else {
#pragma unroll
                    for (int g = 0; g < 4; ++g) {
                        ushort4 pk;
#pragma unroll
                        for (int e = 0; e < 4; ++e) {
                            const int srow = st * 32 + 8 * g + 4 * hi + e;
                            float v = sacc[st2][tt2][4 * g + e];
                            if (srow >= trow) v = 0.0f;   // strict lower: keep s < t
                            ((unsigned short*)&pk)[e] = f2bf(v);
                        }
                        *(ushort4*)(pbase + 8 * g) = pk;
                    }
                }
            }
        }
        __syncthreads();

        // ---- O-phase: oacc += P * V ----
#pragma unroll
        for (int kc = 0; kc < 8; ++kc) {
            short8 pf0 = *(const short8*)&ps[((2 * ws + 0) * 32 + l31) * LDP +
                                             kc * 16 + hi * 8 + swz];
            short8 pf1 = *(const short8*)&ps[((2 * ws + 1) * 32 + l31) * LDP +
                                             kc * 16 + hi * 8 + swz];
            oacc[0] = mfma32(pf0, vf[kc], oacc[0]);
            oacc[1] = mfma32(pf1, vf[kc], oacc[1]);
        }

        if (sb < qb) {
#pragma unroll
            for (int st2 = 0; st2 < 2; ++st2)
#pragma unroll
                for (int kc = 0; kc < 4; ++kc)
                    ak[st2][kc] = akn[st2][kc];
        }
    }

    // ---- epilogue: fp32 store, C-layout (verified orientation) ----
#pragma unroll
    for (int mt2 = 0; mt2 < 2; ++mt2) {
        const int mt = 2 * ws + mt2;
#pragma unroll
        for (int r = 0; r < 16; ++r) {
            const int rl = (r & 3) + 8 * (r >> 2) + 4 * hi;
            out_h[(size_t)(t0 + mt * 32 + rl) * NDIM + wt * 32 + l31] = oacc[mt2][r];
        }
    }
}

extern "C" void kernel_launch(void* const* d_in, const int* in_sizes, int n_in,
                              void* d_out, int out_size, void* d_ws, size_t ws_size,
                              hipStream_t stream) {
    (void)in_sizes; (void)n_in; (void)out_size; (void)ws_size;
    const float* Q = (const float*)d_in[0];
    const float* V = (const float*)d_in[1];
    float* out = (float*)d_out;

    unsigned short* qf  = (unsigned short*)d_ws;           // 16 MB bf16, frag layout
    unsigned short* vfr = qf + (size_t)BH * TN;            // 16 MB bf16, frag layout

    rope_kernel<<<BH * 128, 256, 0, stream>>>(Q, qf);
    vtrans_kernel<<<dim3(T_SEQ / 128, BH), 256, 0, stream>>>(V, vfr);
    attn_kernel<<<BH * 32, 256, 0, stream>>>(qf, vfr, out);
}